// Round 10
// baseline (174.597 us; speedup 1.0000x reference)
//
#include <hip/hip_runtime.h>
#include <stdint.h>
#include <math.h>

#define LSEQ 1024
#define NB 4
#define DM 768
#define NHEAD 12
#define HD 64
#define LVALID 960
#define WIN 512

typedef unsigned short u16;
typedef __attribute__((ext_vector_type(8))) short s16x8;   // 8 bf16 (4 VGPRs)
typedef __attribute__((ext_vector_type(4))) float f32x4;

__device__ __forceinline__ u16 f2bf(float f) {
  union { float f; uint32_t u; } v; v.f = f;
  uint32_t r = v.u + 0x7fffu + ((v.u >> 16) & 1u);
  return (u16)(r >> 16);
}
__device__ __forceinline__ float bf2f(u16 h) {
  union { uint32_t u; float f; } v; v.u = ((uint32_t)h) << 16;
  return v.f;
}
// XOR swizzle of 16B chunks within 128B rows: row has 8 chunks of 8 u16.
__device__ __forceinline__ int swz8(int row, int chunk) {
  return row * 8 + (chunk ^ (row & 7));
}

// async global->LDS, 16B per lane; LDS dest = wave-uniform base + lane*16
__device__ __forceinline__ void gload_lds16(const void* g, void* l) {
  __builtin_amdgcn_global_load_lds(
      (const __attribute__((address_space(1))) unsigned int*)g,
      (__attribute__((address_space(3))) unsigned int*)l, 16, 0, 0);
}

// raw barrier (NO implicit vmcnt/lgkmcnt drain) + compiler memory fence
#define BARW()                                  \
  do {                                          \
    asm volatile("" ::: "memory");              \
    __builtin_amdgcn_s_barrier();               \
    asm volatile("" ::: "memory");              \
  } while (0)
#define LGKM0() asm volatile("s_waitcnt lgkmcnt(0)" ::: "memory")
#define VMC6() asm volatile("s_waitcnt vmcnt(6)" ::: "memory")
#define VMC0() asm volatile("s_waitcnt vmcnt(0)" ::: "memory")

struct WPtrs { const float* w[6]; };
struct GemmPtrs { const u16* wt[6]; const float* bias[6]; u16* out[6]; };

// ---------- fused prep: weight transpose+cast (blocks 0..863) + x cast ----------
__global__ __launch_bounds__(256) void prep(const float* __restrict__ x, u16* __restrict__ xb,
                                            WPtrs P, u16* __restrict__ wtb) {
  int bi = blockIdx.x;
  if (bi >= 864) {
    int i = ((bi - 864) * 256 + threadIdx.x) * 8;
    float4 a = *(const float4*)(x + i);
    float4 bq = *(const float4*)(x + i + 4);
    u16 t[8];
    t[0] = f2bf(a.x); t[1] = f2bf(a.y); t[2] = f2bf(a.z); t[3] = f2bf(a.w);
    t[4] = f2bf(bq.x); t[5] = f2bf(bq.y); t[6] = f2bf(bq.z); t[7] = f2bf(bq.w);
    *(uint4*)(xb + i) = *(uint4*)t;
    return;
  }
  int mat = bi / 144, rem = bi - mat * 144;
  int gx = rem % 12, gy = rem / 12;
  const float* W = P.w[mat];
  u16* Wt = wtb + (size_t)mat * DM * DM;
  __shared__ u16 tile[64][72];
  int k0 = gx * 64, n0 = gy * 64;
  int r4 = threadIdx.x >> 4;          // 0..15
  int c4 = (threadIdx.x & 15) * 4;    // 0..60 step 4
#pragma unroll
  for (int it = 0; it < 4; it++) {
    int r = it * 16 + r4;
    float4 v = *(const float4*)(W + (size_t)(k0 + r) * DM + n0 + c4);
    tile[c4 + 0][r] = f2bf(v.x);
    tile[c4 + 1][r] = f2bf(v.y);
    tile[c4 + 2][r] = f2bf(v.z);
    tile[c4 + 3][r] = f2bf(v.w);
  }
  __syncthreads();
  int rw = threadIdx.x >> 3, cw = (threadIdx.x & 7) * 8;  // 8 lanes/row, 16B each
#pragma unroll
  for (int it = 0; it < 2; it++) {
    int r = it * 32 + rw;
    *(uint4*)(Wt + (size_t)(n0 + r) * DM + k0 + cw) = *(uint4*)&tile[r][cw];
  }
}

// ---------- fused 6-matrix GEMM: 256x256 tile, BK=64, 8-wave 8-phase schedule ----
// R6-proven version (counted-vmcnt deep ledger is load-bearing; TLP/XCD/ledger
// depth all proven neutral; epilogue chunk-XOR killed the 516K bank conflicts).
// FROZEN per R7 verdict.
__global__ __launch_bounds__(512, 2) void gemm6(const u16* __restrict__ Xb, GemmPtrs P) {
  int bid = blockIdx.x;               // 0..251
  int xcd = bid & 7;
  int slot = bid >> 3;                // 0..31 (xcd<4) or 0..30 (xcd>=4)
  int mat, xt, yt;
  if (slot < 30) {
    int s = slot >> 1;                // 0..14 -> (mat, y)
    int xl = slot & 1;
    int mm = s / 3;
    mat = (mm < 3) ? mm : mm + 1;     // {0,1,2,4,5}
    yt = s - mm * 3;
    xt = xcd * 2 + xl;
  } else {
    int j = xcd + 8 * (slot - 30);    // 0..11 bijective
    mat = 3;
    xt = (j / 3) * 4;                 // batch-start tiles {0,4,8,12}
    yt = j - (j / 3) * 3;
  }
  int m0 = xt * 256, n0 = yt * 256;

  __shared__ __align__(16) u16 SMEM[65536];  // 128 KiB: 2 buf x {A 2x128x64 | B 2x128x64}
  const u16* Wt = P.wt[mat];
  int tid = threadIdx.x;
  int w = tid >> 6, lane = tid & 63, qd = lane >> 4, l16 = lane & 15;
  int wm = w >> 2, wn = w & 3;  // 2 M-warps x 4 N-warps, each 128x64 of C
  int cx = l16 & 7;

  f32x4 acc[8][4];
  const f32x4 fz = {0.f, 0.f, 0.f, 0.f};
#pragma unroll
  for (int i = 0; i < 8; i++)
#pragma unroll
    for (int j = 0; j < 4; j++) acc[i][j] = fz;

  // staging source offsets: slot s = j*512+tid; half-tile = 128 rows x 64 cols
  int aoff[2][2], boff[2][2];
#pragma unroll
  for (int j = 0; j < 2; j++) {
    int s = j * 512 + tid;
    int row = s >> 3;
    int col = ((s & 7) ^ (row & 7)) * 8;
#pragma unroll
    for (int h = 0; h < 2; h++) {
      aoff[j][h] = (m0 + h * 128 + row) * DM + col;
      boff[j][h] = (n0 + h * 128 + row) * DM + col;
    }
  }

  auto stageA = [&](int t, int h) {
#pragma unroll
    for (int j = 0; j < 2; j++)
      gload_lds16(Xb + (size_t)aoff[j][h] + t * 64,
                  &SMEM[(t & 1) * 32768 + h * 8192 + (j * 512 + w * 64) * 8]);
  };
  auto stageB = [&](int t, int h) {
#pragma unroll
    for (int j = 0; j < 2; j++)
      gload_lds16(Wt + (size_t)boff[j][h] + t * 64,
                  &SMEM[(t & 1) * 32768 + 16384 + h * 8192 + (j * 512 + w * 64) * 8]);
  };

  // ---- prologue: A(0), B(0), B(1), A(1)h0; A(1)h1 comes at tile0 P1 ----
  stageA(0, 0); stageA(0, 1);
  stageB(0, 0); stageB(0, 1);
  stageB(1, 0); stageB(1, 1);
  stageA(1, 0);
  VMC6();  // A(0)+B(0) landed; B(1)+A(1)h0 (6 loads) still in flight
  BARW();

  const int rB = (wn & 1) * 64 + l16;

  auto tile = [&](int u) {
    const int buf = u & 1;
    const u16* Ab = &SMEM[buf * 32768 + wm * 8192];
    const u16* Bb = &SMEM[buf * 32768 + 16384 + (wn >> 1) * 8192];
    s16x8 af[4][2], bfr[4][2];
    // ---------------- P1 ----------------
#pragma unroll
    for (int mi = 0; mi < 4; mi++)
#pragma unroll
      for (int ks = 0; ks < 2; ks++)
        af[mi][ks] = *(const s16x8*)(Ab + (mi * 16 + l16) * 64 + ((ks * 4 + qd) ^ cx) * 8);
#pragma unroll
    for (int ni = 0; ni < 2; ni++)
#pragma unroll
      for (int ks = 0; ks < 2; ks++)
        bfr[ni][ks] = *(const s16x8*)(Bb + (rB + ni * 16) * 64 + ((ks * 4 + qd) ^ cx) * 8);
    if (u <= 10) stageA(u + 1, 1);
    BARW();
    LGKM0();
    __builtin_amdgcn_s_setprio(1);
#pragma unroll
    for (int mi = 0; mi < 4; mi++)
#pragma unroll
      for (int ni = 0; ni < 2; ni++)
#pragma unroll
        for (int ks = 0; ks < 2; ks++)
          acc[mi][ni] = __builtin_amdgcn_mfma_f32_16x16x32_bf16(af[mi][ks], bfr[ni][ks],
                                                                acc[mi][ni], 0, 0, 0);
    __builtin_amdgcn_s_setprio(0);
    BARW();
    // ---------------- P2 ----------------
#pragma unroll
    for (int ni = 2; ni < 4; ni++)
#pragma unroll
      for (int ks = 0; ks < 2; ks++)
        bfr[ni][ks] = *(const s16x8*)(Bb + (rB + ni * 16) * 64 + ((ks * 4 + qd) ^ cx) * 8);
    BARW();
    LGKM0();
    __builtin_amdgcn_s_setprio(1);
#pragma unroll
    for (int mi = 0; mi < 4; mi++)
#pragma unroll
      for (int ni = 2; ni < 4; ni++)
#pragma unroll
        for (int ks = 0; ks < 2; ks++)
          acc[mi][ni] = __builtin_amdgcn_mfma_f32_16x16x32_bf16(af[mi][ks], bfr[ni][ks],
                                                                acc[mi][ni], 0, 0, 0);
    __builtin_amdgcn_s_setprio(0);
    BARW();
    // ---------------- P3 ----------------
#pragma unroll
    for (int mi = 0; mi < 4; mi++)
#pragma unroll
      for (int ks = 0; ks < 2; ks++)
        af[mi][ks] = *(const s16x8*)(Ab + ((mi + 4) * 16 + l16) * 64 + ((ks * 4 + qd) ^ cx) * 8);
    if (u <= 9) stageB(u + 2, 0);
    BARW();
    LGKM0();
    __builtin_amdgcn_s_setprio(1);
#pragma unroll
    for (int mi = 0; mi < 4; mi++)
#pragma unroll
      for (int ni = 0; ni < 2; ni++)
#pragma unroll
        for (int ks = 0; ks < 2; ks++)
          acc[mi + 4][ni] = __builtin_amdgcn_mfma_f32_16x16x32_bf16(af[mi][ks], bfr[ni][ks],
                                                                    acc[mi + 4][ni], 0, 0, 0);
    __builtin_amdgcn_s_setprio(0);
    BARW();
    // ---------------- P4 ----------------
    if (u <= 9) {
      stageB(u + 2, 1);
      stageA(u + 2, 0);
      VMC6();
    } else {
      VMC0();  // drain: nothing staged beyond the last tile
    }
    BARW();
    __builtin_amdgcn_s_setprio(1);
#pragma unroll
    for (int mi = 0; mi < 4; mi++)
#pragma unroll
      for (int ni = 2; ni < 4; ni++)
#pragma unroll
        for (int ks = 0; ks < 2; ks++)
          acc[mi + 4][ni] = __builtin_amdgcn_mfma_f32_16x16x32_bf16(af[mi][ks], bfr[ni][ks],
                                                                    acc[mi + 4][ni], 0, 0, 0);
    __builtin_amdgcn_s_setprio(0);
    BARW();
  };

  for (int u = 0; u < 12; ++u) tile(u);

  // ---- epilogue: acc -> bf16 C tile in LDS (chunk-swizzled) -> uint4 stores ----
  const float* bias = P.bias[mat];
  u16* outp = P.out[mat];
  __syncthreads();
  u16* Cs = &SMEM[0];  // 256 rows x 32 chunks of 16B (chunk index XOR-swizzled)
#pragma unroll
  for (int ni = 0; ni < 4; ni++) {
    int n = wn * 64 + ni * 16 + l16;
    float bvl = bias[n0 + n];
#pragma unroll
    for (int mi = 0; mi < 8; mi++) {
      int mb = wm * 128 + mi * 16 + qd * 4;
#pragma unroll
      for (int r = 0; r < 4; r++) {
        int rowp = mb + r;
        int sw = ((rowp >> 2) & 3) << 1;  // == qd<<1
        Cs[rowp * 256 + ((((n >> 3) ^ sw) << 3) | (n & 7))] = f2bf(acc[mi][ni][r] + bvl);
      }
    }
  }
  __syncthreads();
#pragma unroll
  for (int it = 0; it < 16; it++) {
    int c = it * 512 + tid;          // logical uint4 chunk id: 8192 chunks
    int row = c >> 5, col = c & 31;  // 32 chunks per 256-wide row
    int sw = ((row >> 2) & 3) << 1;
    uint4 v = ((const uint4*)Cs)[row * 32 + (col ^ sw)];
    *(uint4*)(outp + (size_t)(m0 + row) * DM + n0 + col * 8) = v;
  }
}

// ---------- Vl -> Vt transpose: [4096,768] -> [B,H,HD,LSEQ], coalesced both sides ----
__global__ __launch_bounds__(256) void vt_tr(const u16* __restrict__ Vl, u16* __restrict__ Vt) {
  int bi = blockIdx.x;                  // 768 = 16 t-tiles x 12 h x 4 b
  int tt = bi & 15, hb = bi >> 4;
  int h = hb % NHEAD, b = hb / NHEAD;
  __shared__ u16 tile[64][72];          // 72 pad; row base 144B = 16B-aligned
  int t0 = tt * 64;
  int tid = threadIdx.x;
#pragma unroll
  for (int it = 0; it < 2; it++) {
    int u = it * 256 + tid;
    int r = u >> 3, cc = u & 7;
    uint4 v = *(const uint4*)(Vl + (size_t)(b * LSEQ + t0 + r) * DM + h * HD + cc * 8);
    *(uint4*)&tile[r][cc * 8] = v;
  }
  __syncthreads();
#pragma unroll
  for (int it = 0; it < 2; it++) {
    int u = it * 256 + tid;
    int dd = u >> 3, tc = u & 7;
    u16 pk[8];
#pragma unroll
    for (int j = 0; j < 8; j++) pk[j] = tile[tc * 8 + j][dd];
    *(uint4*)(Vt + ((size_t)((b * NHEAD + h) * HD) + dd) * LSEQ + t0 + tc * 8) = *(uint4*)pk;
  }
}

// ---------- local (banded + global-key) flash attention ----------
// R8-proven: K-tile 128, 64-row q-tiles, 4 waves, single-buffered staging,
// 40 KB LDS, fullvalid fast path, XCD chunking. FROZEN (stage-event axis
// saturated R8; de-staging/dbuf banned R2/R3; fusion with attn_global failed
// verification R9 with unexplained mechanism -- keep separate launches).
__global__ __launch_bounds__(256) void attn_local(
    const u16* __restrict__ Qb, const u16* __restrict__ Kb,
    const u16* __restrict__ Vt, float* __restrict__ out) {
  int bid = blockIdx.x;                       // 0..719; 720 % 8 == 0
  int wid = (bid & 7) * 90 + (bid >> 3);      // bijective XCD chunking
  int q0 = (wid % 15) * 64;
  int hb = wid / 15;
  int h = hb % NHEAD, b = hb / NHEAD;
  __shared__ u16 Ks[128 * 64];                // 128 key-rows x 64 d   (16 KB)
  __shared__ u16 Vs[64 * 128];                // 64 d-rows x 128 keys  (16 KB)
  __shared__ u16 Ps[4][16 * 64];              // 8 KB
  int tid = threadIdx.x, w = tid >> 6, lane = tid & 63, qd = lane >> 4, l16 = lane & 15;

  // K staging: 1024 slots (128 rows x 8 chunks of 16B), 4 per thread
  int rowK[4], colK[4];
#pragma unroll
  for (int i = 0; i < 4; i++) {
    int s = (w * 4 + i) * 64 + lane;
    rowK[i] = s >> 3;
    colK[i] = ((s & 7) ^ (rowK[i] & 7)) * 8;
  }
  // V staging: 1024 slots (64 rows x 16 chunks of 16B), 4 per thread
  int rowV[4], colV[4];
#pragma unroll
  for (int i = 0; i < 4; i++) {
    int s = (w * 4 + i) * 64 + lane;
    rowV[i] = s >> 4;
    colV[i] = ((s & 15) ^ (rowV[i] & 15)) * 8;
  }

  // Q fragments straight from global (wave w owns rows q0+w*16 .. +15)
  const u16* qrow = Qb + (size_t)(b * LSEQ + q0 + w * 16 + l16) * DM + h * HD;
  s16x8 af0 = *(const s16x8*)(qrow + qd * 8);
  s16x8 af1 = *(const s16x8*)(qrow + 32 + qd * 8);

  float l_part[4] = {0.f, 0.f, 0.f, 0.f};
  f32x4 aO[4];
  const f32x4 fz = {0.f, 0.f, 0.f, 0.f};
#pragma unroll
  for (int nt = 0; nt < 4; nt++) aO[nt] = fz;

  for (int c = 0; c < 8; c++) {
    int kb = c * 128;
    if (c > 0 && !(kb < LVALID && kb + 127 >= q0 - WIN && kb <= q0 + 63 + WIN)) continue;
    __syncthreads();
#pragma unroll
    for (int i = 0; i < 4; i++) {
      gload_lds16(Kb + (size_t)(b * LSEQ + kb + rowK[i]) * DM + h * HD + colK[i],
                  Ks + (size_t)(w * 4 + i) * 512);
      gload_lds16(Vt + (size_t)((b * NHEAD + h) * HD + rowV[i]) * LSEQ + kb + colV[i],
                  Vs + (size_t)(w * 4 + i) * 512);
    }
    __syncthreads();

#pragma unroll
    for (int sub = 0; sub < 2; sub++) {
      int kbs = kb + sub * 64;
      // identical predicate to R6's 64-tile visit set (+0-granules skipped)
      if (!((c == 0 && sub == 0) ||
            (kbs < LVALID && kbs + 63 >= q0 - WIN && kbs <= q0 + 63 + WIN)))
        continue;
      bool fullvalid =
          (kbs + 63 < LVALID) && (kbs + 63 <= q0 + WIN) && (q0 + 63 <= kbs + WIN);
      float p[4][4];
#pragma unroll
      for (int nt = 0; nt < 4; nt++) {
        s16x8 bk0 = *(const s16x8*)(Ks + swz8(sub * 64 + nt * 16 + l16, qd) * 8);
        s16x8 bk1 = *(const s16x8*)(Ks + swz8(sub * 64 + nt * 16 + l16, 4 + qd) * 8);
        f32x4 s = fz;
        s = __builtin_amdgcn_mfma_f32_16x16x32_bf16(af0, bk0, s, 0, 0, 0);
        s = __builtin_amdgcn_mfma_f32_16x16x32_bf16(af1, bk1, s, 0, 0, 0);
        if (fullvalid) {
#pragma unroll
          for (int r = 0; r < 4; r++) {
            p[nt][r] = __expf(s[r] * 0.125f);
            l_part[r] += p[nt][r];
          }
        } else {
          int k = kbs + nt * 16 + l16;
#pragma unroll
          for (int r = 0; r < 4; r++) {
            int q = q0 + w * 16 + qd * 4 + r;
            bool valid = (k < 8) || (k < LVALID && (k - q) <= WIN && (q - k) <= WIN);
            float sv = valid ? s[r] * 0.125f : -1e30f;
            p[nt][r] = __expf(sv);      // masked -> exp(-1e30) = 0 exactly
            l_part[r] += p[nt][r];
          }
        }
      }

      // P (C-layout) -> wave-private LDS -> A-layout fragments
#pragma unroll
      for (int nt = 0; nt < 4; nt++) {
        int chunk = nt * 2 + (l16 >> 3);
        int within = l16 & 7;
#pragma unroll
        for (int r = 0; r < 4; r++) {
          int qrow2 = qd * 4 + r;
          Ps[w][swz8(qrow2, chunk) * 8 + within] = f2bf(p[nt][r]);
        }
      }

      s16x8 pf0 = *(const s16x8*)(&Ps[w][0] + swz8(l16, qd) * 8);
      s16x8 pf1 = *(const s16x8*)(&Ps[w][0] + swz8(l16, 4 + qd) * 8);
#pragma unroll
      for (int nt = 0; nt < 4; nt++) {
        int vrow = nt * 16 + l16;
        s16x8 v0 = *(const s16x8*)(Vs + (vrow * 16 + ((sub * 8 + qd) ^ (vrow & 15))) * 8);
        s16x8 v1 = *(const s16x8*)(Vs + (vrow * 16 + ((sub * 8 + 4 + qd) ^ (vrow & 15))) * 8);
        aO[nt] = __builtin_amdgcn_mfma_f32_16x16x32_bf16(pf0, v0, aO[nt], 0, 0, 0);
        aO[nt] = __builtin_amdgcn_mfma_f32_16x16x32_bf16(pf1, v1, aO[nt], 0, 0, 0);
      }
    }
  }

  // one deferred row-sum reduction (16 lanes of the qd-group hold same q-row)
#pragma unroll
  for (int off = 1; off < 16; off <<= 1)
#pragma unroll
    for (int r = 0; r < 4; r++) l_part[r] += __shfl_xor(l_part[r], off);
  float inv[4];
#pragma unroll
  for (int r = 0; r < 4; r++) inv[r] = 1.0f / l_part[r];
#pragma unroll
  for (int nt = 0; nt < 4; nt++)
#pragma unroll
    for (int r = 0; r < 4; r++) {
      int q = q0 + w * 16 + qd * 4 + r;
      out[(size_t)(b * LSEQ + q) * DM + h * HD + nt * 16 + l16] = aO[nt][r] * inv[r];
    }
}

// ---------- global attention for queries 0..7 + zero tail rows 960..1023 ----------
// 1024 threads (16 waves): serial-latency-bound kernel; PV chain 15 iters.
__global__ __launch_bounds__(1024) void attn_global(
    const u16* __restrict__ Qgb, const u16* __restrict__ Kgb,
    const u16* __restrict__ Vgb, float* __restrict__ out) {
  int h = blockIdx.x, b = blockIdx.y;
  __shared__ float p_lds[8][960];        // 30 KB
  __shared__ float partial[16][8][64];   // 32 KB
  int tid = threadIdx.x, w = tid >> 6, lane = tid & 63, qd = lane >> 4, l16 = lane & 15;

  {
    float4 z = {0.f, 0.f, 0.f, 0.f};
    int r = tid >> 4, cc = tid & 15;     // 1024 float4 = 64 rows x 16 chunks
    *(float4*)(out + (size_t)(b * LSEQ + LVALID + r) * DM + h * HD + cc * 4) = z;
  }

  const u16* qbase = Qgb + (size_t)(b * LSEQ + l16) * DM + h * HD;
  s16x8 af0 = *(const s16x8*)(qbase + qd * 8);
  s16x8 af1 = *(const s16x8*)(qbase + 32 + qd * 8);
  const f32x4 fz = {0.f, 0.f, 0.f, 0.f};
#pragma unroll
  for (int t = 0; t < 4; t++) {
    int idx = w + 16 * t;                // 64 slots cover 60 16-key tiles
    if (idx < 60) {
      int kb = idx * 16;
      const u16* kbase = Kgb + (size_t)(b * LSEQ + kb + l16) * DM + h * HD;
      s16x8 bk0 = *(const s16x8*)(kbase + qd * 8);
      s16x8 bk1 = *(const s16x8*)(kbase + 32 + qd * 8);
      f32x4 s = fz;
      s = __builtin_amdgcn_mfma_f32_16x16x32_bf16(af0, bk0, s, 0, 0, 0);
      s = __builtin_amdgcn_mfma_f32_16x16x32_bf16(af1, bk1, s, 0, 0, 0);
      if (qd < 2) {
#pragma unroll
        for (int r = 0; r < 4; r++)
          p_lds[qd * 4 + r][kb + l16] = s[r] * 0.125f;
      }
    }
  }
  __syncthreads();

  if (w < 8) {
    int q = w;
    float m = -1e30f;
#pragma unroll
    for (int ki = 0; ki < 15; ki++) m = fmaxf(m, p_lds[q][ki * 64 + lane]);
#pragma unroll
    for (int off = 1; off < 64; off <<= 1) m = fmaxf(m, __shfl_xor(m, off));
    float e[15], ssum = 0.f;
#pragma unroll
    for (int ki = 0; ki < 15; ki++) {
      e[ki] = __expf(p_lds[q][ki * 64 + lane] - m);
      ssum += e[ki];
    }
#pragma unroll
    for (int off = 1; off < 64; off <<= 1) ssum += __shfl_xor(ssum, off);
    float inv = 1.0f / ssum;
#pragma unroll
    for (int ki = 0; ki < 15; ki++) p_lds[q][ki * 64 + lane] = e[ki] * inv;
  }
  __syncthreads();

  float acc[8] = {0.f, 0.f, 0.f, 0.f, 0.f, 0.f, 0.f, 0.f};
  const u16* vcol = Vgb + (size_t)b * LSEQ * DM + h * HD + lane;
  for (int kg = 0; kg < 15; kg++) {
    int k0 = w * 60 + kg * 4;
    float v0 = bf2f(vcol[(size_t)(k0 + 0) * DM]);
    float v1 = bf2f(vcol[(size_t)(k0 + 1) * DM]);
    float v2 = bf2f(vcol[(size_t)(k0 + 2) * DM]);
    float v3 = bf2f(vcol[(size_t)(k0 + 3) * DM]);
#pragma unroll
    for (int q = 0; q < 8; q++) {
      float4 p4 = *(const float4*)&p_lds[q][k0];
      acc[q] += p4.x * v0 + p4.y * v1 + p4.z * v2 + p4.w * v3;
    }
  }
#pragma unroll
  for (int q = 0; q < 8; q++) partial[w][q][lane] = acc[q];
  __syncthreads();
  if (tid < 512) {
    int q = tid >> 6, d = tid & 63;
    float sum = 0.f;
#pragma unroll
    for (int i = 0; i < 16; i++) sum += partial[i][q][d];
    out[(size_t)(b * LSEQ + q) * DM + h * HD + d] = sum;
  }
}

extern "C" void kernel_launch(void* const* d_in, const int* in_sizes, int n_in,
                              void* d_out, int out_size, void* d_ws, size_t ws_size,
                              hipStream_t stream) {
  const float* x = (const float*)d_in[0];
  float* out = (float*)d_out;
  char* ws = (char*)d_ws;

  const size_t XB_SZ = (size_t)4096 * DM * 2;
  const size_t WT_SZ = (size_t)6 * DM * DM * 2;
  const size_t MAT_SZ = (size_t)4096 * DM;
  u16* Xb = (u16*)ws;
  u16* Wt = (u16*)(ws + XB_SZ);
  u16* QKV = (u16*)(ws + XB_SZ + WT_SZ);
  u16* Vt = (u16*)(ws + XB_SZ + WT_SZ + (size_t)6 * MAT_SZ * 2);

  u16* Ql = QKV + 0 * MAT_SZ;
  u16* Kl = QKV + 1 * MAT_SZ;
  u16* Vl = QKV + 2 * MAT_SZ;
  u16* Qg = QKV + 3 * MAT_SZ;
  u16* Kg = QKV + 4 * MAT_SZ;
  u16* Vg = QKV + 5 * MAT_SZ;

  WPtrs wp;
  wp.w[0] = (const float*)d_in[1];
  wp.w[1] = (const float*)d_in[3];
  wp.w[2] = (const float*)d_in[5];
  wp.w[3] = (const float*)d_in[7];
  wp.w[4] = (const float*)d_in[9];
  wp.w[5] = (const float*)d_in[11];
  prep<<<2400, 256, 0, stream>>>(x, Xb, wp, Wt);

  GemmPtrs gp;
  const int bidx[6] = {2, 4, 6, 8, 10, 12};
  u16* outs[6] = {Ql, Kl, Vl, Qg, Kg, Vg};
  for (int i = 0; i < 6; i++) {
    gp.wt[i] = Wt + (size_t)i * DM * DM;
    gp.bias[i] = (const float*)d_in[bidx[i]];
    gp.out[i] = outs[i];
  }
  gemm6<<<252, 512, 0, stream>>>(Xb, gp);

  vt_tr<<<768, 256, 0, stream>>>(Vl, Vt);

  attn_local<<<720, 256, 0, stream>>>(Ql, Kl, Vt, out);
  attn_global<<<dim3(12, 4), 1024, 0, stream>>>(Qg, Kg, Vg, out);
}

// Round 11
// 169.191 us; speedup vs baseline: 1.0319x; 1.0319x over previous
//
#include <hip/hip_runtime.h>
#include <stdint.h>
#include <math.h>

#define LSEQ 1024
#define NB 4
#define DM 768
#define NHEAD 12
#define HD 64
#define LVALID 960
#define WIN 512

typedef unsigned short u16;
typedef __attribute__((ext_vector_type(8))) short s16x8;   // 8 bf16 (4 VGPRs)
typedef __attribute__((ext_vector_type(4))) float f32x4;

__device__ __forceinline__ u16 f2bf(float f) {
  union { float f; uint32_t u; } v; v.f = f;
  uint32_t r = v.u + 0x7fffu + ((v.u >> 16) & 1u);
  return (u16)(r >> 16);
}
__device__ __forceinline__ float bf2f(u16 h) {
  union { uint32_t u; float f; } v; v.u = ((uint32_t)h) << 16;
  return v.f;
}
// XOR swizzle of 16B chunks within 128B rows: row has 8 chunks of 8 u16.
__device__ __forceinline__ int swz8(int row, int chunk) {
  return row * 8 + (chunk ^ (row & 7));
}

// async global->LDS, 16B per lane; LDS dest = wave-uniform base + lane*16
__device__ __forceinline__ void gload_lds16(const void* g, void* l) {
  __builtin_amdgcn_global_load_lds(
      (const __attribute__((address_space(1))) unsigned int*)g,
      (__attribute__((address_space(3))) unsigned int*)l, 16, 0, 0);
}

// raw barrier (NO implicit vmcnt/lgkmcnt drain) + compiler memory fence
#define BARW()                                  \
  do {                                          \
    asm volatile("" ::: "memory");              \
    __builtin_amdgcn_s_barrier();               \
    asm volatile("" ::: "memory");              \
  } while (0)
#define LGKM0() asm volatile("s_waitcnt lgkmcnt(0)" ::: "memory")
#define VMC6() asm volatile("s_waitcnt vmcnt(6)" ::: "memory")
#define VMC0() asm volatile("s_waitcnt vmcnt(0)" ::: "memory")

struct WPtrs { const float* w[6]; };
struct GemmPtrs { const u16* wt[6]; const float* bias[6]; u16* out[6]; };

// ---------- fused prep: weight transpose+cast (blocks 0..863) + x cast ----------
__global__ __launch_bounds__(256) void prep(const float* __restrict__ x, u16* __restrict__ xb,
                                            WPtrs P, u16* __restrict__ wtb) {
  int bi = blockIdx.x;
  if (bi >= 864) {
    int i = ((bi - 864) * 256 + threadIdx.x) * 8;
    float4 a = *(const float4*)(x + i);
    float4 bq = *(const float4*)(x + i + 4);
    u16 t[8];
    t[0] = f2bf(a.x); t[1] = f2bf(a.y); t[2] = f2bf(a.z); t[3] = f2bf(a.w);
    t[4] = f2bf(bq.x); t[5] = f2bf(bq.y); t[6] = f2bf(bq.z); t[7] = f2bf(bq.w);
    *(uint4*)(xb + i) = *(uint4*)t;
    return;
  }
  int mat = bi / 144, rem = bi - mat * 144;
  int gx = rem % 12, gy = rem / 12;
  const float* W = P.w[mat];
  u16* Wt = wtb + (size_t)mat * DM * DM;
  __shared__ u16 tile[64][72];
  int k0 = gx * 64, n0 = gy * 64;
  int r4 = threadIdx.x >> 4;          // 0..15
  int c4 = (threadIdx.x & 15) * 4;    // 0..60 step 4
#pragma unroll
  for (int it = 0; it < 4; it++) {
    int r = it * 16 + r4;
    float4 v = *(const float4*)(W + (size_t)(k0 + r) * DM + n0 + c4);
    tile[c4 + 0][r] = f2bf(v.x);
    tile[c4 + 1][r] = f2bf(v.y);
    tile[c4 + 2][r] = f2bf(v.z);
    tile[c4 + 3][r] = f2bf(v.w);
  }
  __syncthreads();
  int rw = threadIdx.x >> 3, cw = (threadIdx.x & 7) * 8;  // 8 lanes/row, 16B each
#pragma unroll
  for (int it = 0; it < 2; it++) {
    int r = it * 32 + rw;
    *(uint4*)(Wt + (size_t)(n0 + r) * DM + k0 + cw) = *(uint4*)&tile[r][cw];
  }
}

// ---------- fused 6-matrix GEMM: 256x256 tile, BK=64, 8-wave 8-phase schedule ----
// R6-proven version. FROZEN per R7 verdict (counted-vmcnt ledger is the one
// load-bearing lever; TLP/XCD/ledger-depth all neutral; chunk-XOR epilogue
// killed the bank conflicts).
__global__ __launch_bounds__(512, 2) void gemm6(const u16* __restrict__ Xb, GemmPtrs P) {
  int bid = blockIdx.x;               // 0..251
  int xcd = bid & 7;
  int slot = bid >> 3;                // 0..31 (xcd<4) or 0..30 (xcd>=4)
  int mat, xt, yt;
  if (slot < 30) {
    int s = slot >> 1;                // 0..14 -> (mat, y)
    int xl = slot & 1;
    int mm = s / 3;
    mat = (mm < 3) ? mm : mm + 1;     // {0,1,2,4,5}
    yt = s - mm * 3;
    xt = xcd * 2 + xl;
  } else {
    int j = xcd + 8 * (slot - 30);    // 0..11 bijective
    mat = 3;
    xt = (j / 3) * 4;                 // batch-start tiles {0,4,8,12}
    yt = j - (j / 3) * 3;
  }
  int m0 = xt * 256, n0 = yt * 256;

  __shared__ __align__(16) u16 SMEM[65536];  // 128 KiB: 2 buf x {A 2x128x64 | B 2x128x64}
  const u16* Wt = P.wt[mat];
  int tid = threadIdx.x;
  int w = tid >> 6, lane = tid & 63, qd = lane >> 4, l16 = lane & 15;
  int wm = w >> 2, wn = w & 3;  // 2 M-warps x 4 N-warps, each 128x64 of C
  int cx = l16 & 7;

  f32x4 acc[8][4];
  const f32x4 fz = {0.f, 0.f, 0.f, 0.f};
#pragma unroll
  for (int i = 0; i < 8; i++)
#pragma unroll
    for (int j = 0; j < 4; j++) acc[i][j] = fz;

  // staging source offsets: slot s = j*512+tid; half-tile = 128 rows x 64 cols
  int aoff[2][2], boff[2][2];
#pragma unroll
  for (int j = 0; j < 2; j++) {
    int s = j * 512 + tid;
    int row = s >> 3;
    int col = ((s & 7) ^ (row & 7)) * 8;
#pragma unroll
    for (int h = 0; h < 2; h++) {
      aoff[j][h] = (m0 + h * 128 + row) * DM + col;
      boff[j][h] = (n0 + h * 128 + row) * DM + col;
    }
  }

  auto stageA = [&](int t, int h) {
#pragma unroll
    for (int j = 0; j < 2; j++)
      gload_lds16(Xb + (size_t)aoff[j][h] + t * 64,
                  &SMEM[(t & 1) * 32768 + h * 8192 + (j * 512 + w * 64) * 8]);
  };
  auto stageB = [&](int t, int h) {
#pragma unroll
    for (int j = 0; j < 2; j++)
      gload_lds16(Wt + (size_t)boff[j][h] + t * 64,
                  &SMEM[(t & 1) * 32768 + 16384 + h * 8192 + (j * 512 + w * 64) * 8]);
  };

  // ---- prologue: A(0), B(0), B(1), A(1)h0; A(1)h1 comes at tile0 P1 ----
  stageA(0, 0); stageA(0, 1);
  stageB(0, 0); stageB(0, 1);
  stageB(1, 0); stageB(1, 1);
  stageA(1, 0);
  VMC6();  // A(0)+B(0) landed; B(1)+A(1)h0 (6 loads) still in flight
  BARW();

  const int rB = (wn & 1) * 64 + l16;

  auto tile = [&](int u) {
    const int buf = u & 1;
    const u16* Ab = &SMEM[buf * 32768 + wm * 8192];
    const u16* Bb = &SMEM[buf * 32768 + 16384 + (wn >> 1) * 8192];
    s16x8 af[4][2], bfr[4][2];
    // ---------------- P1 ----------------
#pragma unroll
    for (int mi = 0; mi < 4; mi++)
#pragma unroll
      for (int ks = 0; ks < 2; ks++)
        af[mi][ks] = *(const s16x8*)(Ab + (mi * 16 + l16) * 64 + ((ks * 4 + qd) ^ cx) * 8);
#pragma unroll
    for (int ni = 0; ni < 2; ni++)
#pragma unroll
      for (int ks = 0; ks < 2; ks++)
        bfr[ni][ks] = *(const s16x8*)(Bb + (rB + ni * 16) * 64 + ((ks * 4 + qd) ^ cx) * 8);
    if (u <= 10) stageA(u + 1, 1);
    BARW();
    LGKM0();
    __builtin_amdgcn_s_setprio(1);
#pragma unroll
    for (int mi = 0; mi < 4; mi++)
#pragma unroll
      for (int ni = 0; ni < 2; ni++)
#pragma unroll
        for (int ks = 0; ks < 2; ks++)
          acc[mi][ni] = __builtin_amdgcn_mfma_f32_16x16x32_bf16(af[mi][ks], bfr[ni][ks],
                                                                acc[mi][ni], 0, 0, 0);
    __builtin_amdgcn_s_setprio(0);
    BARW();
    // ---------------- P2 ----------------
#pragma unroll
    for (int ni = 2; ni < 4; ni++)
#pragma unroll
      for (int ks = 0; ks < 2; ks++)
        bfr[ni][ks] = *(const s16x8*)(Bb + (rB + ni * 16) * 64 + ((ks * 4 + qd) ^ cx) * 8);
    BARW();
    LGKM0();
    __builtin_amdgcn_s_setprio(1);
#pragma unroll
    for (int mi = 0; mi < 4; mi++)
#pragma unroll
      for (int ni = 2; ni < 4; ni++)
#pragma unroll
        for (int ks = 0; ks < 2; ks++)
          acc[mi][ni] = __builtin_amdgcn_mfma_f32_16x16x32_bf16(af[mi][ks], bfr[ni][ks],
                                                                acc[mi][ni], 0, 0, 0);
    __builtin_amdgcn_s_setprio(0);
    BARW();
    // ---------------- P3 ----------------
#pragma unroll
    for (int mi = 0; mi < 4; mi++)
#pragma unroll
      for (int ks = 0; ks < 2; ks++)
        af[mi][ks] = *(const s16x8*)(Ab + ((mi + 4) * 16 + l16) * 64 + ((ks * 4 + qd) ^ cx) * 8);
    if (u <= 9) stageB(u + 2, 0);
    BARW();
    LGKM0();
    __builtin_amdgcn_s_setprio(1);
#pragma unroll
    for (int mi = 0; mi < 4; mi++)
#pragma unroll
      for (int ni = 0; ni < 2; ni++)
#pragma unroll
        for (int ks = 0; ks < 2; ks++)
          acc[mi + 4][ni] = __builtin_amdgcn_mfma_f32_16x16x32_bf16(af[mi][ks], bfr[ni][ks],
                                                                    acc[mi + 4][ni], 0, 0, 0);
    __builtin_amdgcn_s_setprio(0);
    BARW();
    // ---------------- P4 ----------------
    if (u <= 9) {
      stageB(u + 2, 1);
      stageA(u + 2, 0);
      VMC6();
    } else {
      VMC0();  // drain: nothing staged beyond the last tile
    }
    BARW();
    __builtin_amdgcn_s_setprio(1);
#pragma unroll
    for (int mi = 0; mi < 4; mi++)
#pragma unroll
      for (int ni = 2; ni < 4; ni++)
#pragma unroll
        for (int ks = 0; ks < 2; ks++)
          acc[mi + 4][ni] = __builtin_amdgcn_mfma_f32_16x16x32_bf16(af[mi][ks], bfr[ni][ks],
                                                                    acc[mi + 4][ni], 0, 0, 0);
    __builtin_amdgcn_s_setprio(0);
    BARW();
  };

  for (int u = 0; u < 12; ++u) tile(u);

  // ---- epilogue: acc -> bf16 C tile in LDS (chunk-swizzled) -> uint4 stores ----
  const float* bias = P.bias[mat];
  u16* outp = P.out[mat];
  __syncthreads();
  u16* Cs = &SMEM[0];  // 256 rows x 32 chunks of 16B (chunk index XOR-swizzled)
#pragma unroll
  for (int ni = 0; ni < 4; ni++) {
    int n = wn * 64 + ni * 16 + l16;
    float bvl = bias[n0 + n];
#pragma unroll
    for (int mi = 0; mi < 8; mi++) {
      int mb = wm * 128 + mi * 16 + qd * 4;
#pragma unroll
      for (int r = 0; r < 4; r++) {
        int rowp = mb + r;
        int sw = ((rowp >> 2) & 3) << 1;  // == qd<<1
        Cs[rowp * 256 + ((((n >> 3) ^ sw) << 3) | (n & 7))] = f2bf(acc[mi][ni][r] + bvl);
      }
    }
  }
  __syncthreads();
#pragma unroll
  for (int it = 0; it < 16; it++) {
    int c = it * 512 + tid;          // logical uint4 chunk id: 8192 chunks
    int row = c >> 5, col = c & 31;  // 32 chunks per 256-wide row
    int sw = ((row >> 2) & 3) << 1;
    uint4 v = ((const uint4*)Cs)[row * 32 + (col ^ sw)];
    *(uint4*)(outp + (size_t)(m0 + row) * DM + n0 + col * 8) = v;
  }
}

// ---------- fused: global attention (blocks 0..47) + Vl->Vt transpose (48..239) ----
// Round-11: the two kernels with DISJOINT output tensors (out rows 0..7/960+
// vs the Vt workspace), both depending only on gemm6, fused into one
// 1024-thread launch so the ~4 us transpose hides under the ~6 us global
// path. Unlike R9's failed fusion, NO tensor is co-written by two paths.
// Global body = R5-proven 1024-thread version (verbatim, pointer-arith LDS).
// vt body = R6-proven transpose, 4 jobs/block (256-thread subgroups, private
// 9.2 KB LDS slices; the block-wide barrier is coarser but safe).
__global__ __launch_bounds__(1024) void global_and_vt(
    const u16* __restrict__ Qgb, const u16* __restrict__ Kgb,
    const u16* __restrict__ Vgb, const u16* __restrict__ Vl,
    u16* __restrict__ Vt, float* __restrict__ out) {
  __shared__ __align__(16) u16 SMEM[31744];   // 62 KB: max(30+32 global, 4x9 vt)
  int bid = blockIdx.x;
  int tid = threadIdx.x;

  if (bid < 48) {
    // ============== global-attention path (R5 1024-thread body) ==============
    int h = bid % NHEAD, b = bid / NHEAD;
    float* p_lds = (float*)SMEM;              // [8][960] = 30 KB
    float* partial = p_lds + 8 * 960;         // [16][8][64] = 32 KB
    int w = tid >> 6, lane = tid & 63, qd = lane >> 4, l16 = lane & 15;

    {
      float4 z = {0.f, 0.f, 0.f, 0.f};
      int r = tid >> 4, cc = tid & 15;        // 1024 float4 = 64 rows x 16 chunks
      *(float4*)(out + (size_t)(b * LSEQ + LVALID + r) * DM + h * HD + cc * 4) = z;
    }

    const u16* qbase = Qgb + (size_t)(b * LSEQ + l16) * DM + h * HD;
    s16x8 af0 = *(const s16x8*)(qbase + qd * 8);
    s16x8 af1 = *(const s16x8*)(qbase + 32 + qd * 8);
    const f32x4 fz = {0.f, 0.f, 0.f, 0.f};
#pragma unroll
    for (int t = 0; t < 4; t++) {
      int idx = w + 16 * t;                   // 64 slots cover 60 16-key tiles
      if (idx < 60) {
        int kb = idx * 16;
        const u16* kbase = Kgb + (size_t)(b * LSEQ + kb + l16) * DM + h * HD;
        s16x8 bk0 = *(const s16x8*)(kbase + qd * 8);
        s16x8 bk1 = *(const s16x8*)(kbase + 32 + qd * 8);
        f32x4 s = fz;
        s = __builtin_amdgcn_mfma_f32_16x16x32_bf16(af0, bk0, s, 0, 0, 0);
        s = __builtin_amdgcn_mfma_f32_16x16x32_bf16(af1, bk1, s, 0, 0, 0);
        if (qd < 2) {
#pragma unroll
          for (int r = 0; r < 4; r++)
            p_lds[(qd * 4 + r) * 960 + kb + l16] = s[r] * 0.125f;
        }
      }
    }
    __syncthreads();

    if (w < 8) {
      int q = w;
      float m = -1e30f;
#pragma unroll
      for (int ki = 0; ki < 15; ki++) m = fmaxf(m, p_lds[q * 960 + ki * 64 + lane]);
#pragma unroll
      for (int off = 1; off < 64; off <<= 1) m = fmaxf(m, __shfl_xor(m, off));
      float e[15], ssum = 0.f;
#pragma unroll
      for (int ki = 0; ki < 15; ki++) {
        e[ki] = __expf(p_lds[q * 960 + ki * 64 + lane] - m);
        ssum += e[ki];
      }
#pragma unroll
      for (int off = 1; off < 64; off <<= 1) ssum += __shfl_xor(ssum, off);
      float inv = 1.0f / ssum;
#pragma unroll
      for (int ki = 0; ki < 15; ki++) p_lds[q * 960 + ki * 64 + lane] = e[ki] * inv;
    }
    __syncthreads();

    float acc[8] = {0.f, 0.f, 0.f, 0.f, 0.f, 0.f, 0.f, 0.f};
    const u16* vcol = Vgb + (size_t)b * LSEQ * DM + h * HD + lane;
    for (int kg = 0; kg < 15; kg++) {
      int k0 = w * 60 + kg * 4;
      float v0 = bf2f(vcol[(size_t)(k0 + 0) * DM]);
      float v1 = bf2f(vcol[(size_t)(k0 + 1) * DM]);
      float v2 = bf2f(vcol[(size_t)(k0 + 2) * DM]);
      float v3 = bf2f(vcol[(size_t)(k0 + 3) * DM]);
#pragma unroll
      for (int q = 0; q < 8; q++) {
        float4 p4 = *(const float4*)&p_lds[q * 960 + k0];
        acc[q] += p4.x * v0 + p4.y * v1 + p4.z * v2 + p4.w * v3;
      }
    }
#pragma unroll
    for (int q = 0; q < 8; q++) partial[(w * 8 + q) * 64 + lane] = acc[q];
    __syncthreads();
    if (tid < 512) {
      int q = tid >> 6, d = tid & 63;
      float sum = 0.f;
#pragma unroll
      for (int i = 0; i < 16; i++) sum += partial[(i * 8 + q) * 64 + d];
      out[(size_t)(b * LSEQ + q) * DM + h * HD + d] = sum;
    }
    return;
  }

  // ============== Vl -> Vt transpose path: 4 jobs per 1024-thread block =========
  int job = (bid - 48) * 4 + (tid >> 8);      // 0..767 = 16 t-tiles x 12 h x 4 b
  int t = tid & 255;
  u16* tile = SMEM + (tid >> 8) * 4608;       // [64][72] u16 = 9216 B per job
  int tt = job & 15, hb = job >> 4;
  int h = hb % NHEAD, b = hb / NHEAD;
  int t0 = tt * 64;
#pragma unroll
  for (int it = 0; it < 2; it++) {
    int u = it * 256 + t;
    int r = u >> 3, cc = u & 7;
    uint4 v = *(const uint4*)(Vl + (size_t)(b * LSEQ + t0 + r) * DM + h * HD + cc * 8);
    *(uint4*)&tile[r * 72 + cc * 8] = v;
  }
  __syncthreads();
#pragma unroll
  for (int it = 0; it < 2; it++) {
    int u = it * 256 + t;
    int dd = u >> 3, tc = u & 7;
    u16 pk[8];
#pragma unroll
    for (int j = 0; j < 8; j++) pk[j] = tile[(tc * 8 + j) * 72 + dd];
    *(uint4*)(Vt + ((size_t)((b * NHEAD + h) * HD) + dd) * LSEQ + t0 + tc * 8) = *(uint4*)pk;
  }
}

// ---------- local (banded + global-key) flash attention ----------
// R8-proven body, FROZEN, with one change: runs AFTER the global path now, so
// the final store skips rows 0..7 (owned exclusively by global). Store-only
// predicate; all computation unchanged -> rows 8..959 bitwise identical.
__global__ __launch_bounds__(256) void attn_local(
    const u16* __restrict__ Qb, const u16* __restrict__ Kb,
    const u16* __restrict__ Vt, float* __restrict__ out) {
  int bid = blockIdx.x;                       // 0..719; 720 % 8 == 0
  int wid = (bid & 7) * 90 + (bid >> 3);      // bijective XCD chunking
  int q0 = (wid % 15) * 64;
  int hb = wid / 15;
  int h = hb % NHEAD, b = hb / NHEAD;
  __shared__ u16 Ks[128 * 64];                // 128 key-rows x 64 d   (16 KB)
  __shared__ u16 Vs[64 * 128];                // 64 d-rows x 128 keys  (16 KB)
  __shared__ u16 Ps[4][16 * 64];              // 8 KB
  int tid = threadIdx.x, w = tid >> 6, lane = tid & 63, qd = lane >> 4, l16 = lane & 15;

  // K staging: 1024 slots (128 rows x 8 chunks of 16B), 4 per thread
  int rowK[4], colK[4];
#pragma unroll
  for (int i = 0; i < 4; i++) {
    int s = (w * 4 + i) * 64 + lane;
    rowK[i] = s >> 3;
    colK[i] = ((s & 7) ^ (rowK[i] & 7)) * 8;
  }
  // V staging: 1024 slots (64 rows x 16 chunks of 16B), 4 per thread
  int rowV[4], colV[4];
#pragma unroll
  for (int i = 0; i < 4; i++) {
    int s = (w * 4 + i) * 64 + lane;
    rowV[i] = s >> 4;
    colV[i] = ((s & 15) ^ (rowV[i] & 15)) * 8;
  }

  // Q fragments straight from global (wave w owns rows q0+w*16 .. +15)
  const u16* qrow = Qb + (size_t)(b * LSEQ + q0 + w * 16 + l16) * DM + h * HD;
  s16x8 af0 = *(const s16x8*)(qrow + qd * 8);
  s16x8 af1 = *(const s16x8*)(qrow + 32 + qd * 8);

  float l_part[4] = {0.f, 0.f, 0.f, 0.f};
  f32x4 aO[4];
  const f32x4 fz = {0.f, 0.f, 0.f, 0.f};
#pragma unroll
  for (int nt = 0; nt < 4; nt++) aO[nt] = fz;

  for (int c = 0; c < 8; c++) {
    int kb = c * 128;
    if (c > 0 && !(kb < LVALID && kb + 127 >= q0 - WIN && kb <= q0 + 63 + WIN)) continue;
    __syncthreads();
#pragma unroll
    for (int i = 0; i < 4; i++) {
      gload_lds16(Kb + (size_t)(b * LSEQ + kb + rowK[i]) * DM + h * HD + colK[i],
                  Ks + (size_t)(w * 4 + i) * 512);
      gload_lds16(Vt + (size_t)((b * NHEAD + h) * HD + rowV[i]) * LSEQ + kb + colV[i],
                  Vs + (size_t)(w * 4 + i) * 512);
    }
    __syncthreads();

#pragma unroll
    for (int sub = 0; sub < 2; sub++) {
      int kbs = kb + sub * 64;
      // identical predicate to R6's 64-tile visit set (+0-granules skipped)
      if (!((c == 0 && sub == 0) ||
            (kbs < LVALID && kbs + 63 >= q0 - WIN && kbs <= q0 + 63 + WIN)))
        continue;
      bool fullvalid =
          (kbs + 63 < LVALID) && (kbs + 63 <= q0 + WIN) && (q0 + 63 <= kbs + WIN);
      float p[4][4];
#pragma unroll
      for (int nt = 0; nt < 4; nt++) {
        s16x8 bk0 = *(const s16x8*)(Ks + swz8(sub * 64 + nt * 16 + l16, qd) * 8);
        s16x8 bk1 = *(const s16x8*)(Ks + swz8(sub * 64 + nt * 16 + l16, 4 + qd) * 8);
        f32x4 s = fz;
        s = __builtin_amdgcn_mfma_f32_16x16x32_bf16(af0, bk0, s, 0, 0, 0);
        s = __builtin_amdgcn_mfma_f32_16x16x32_bf16(af1, bk1, s, 0, 0, 0);
        if (fullvalid) {
#pragma unroll
          for (int r = 0; r < 4; r++) {
            p[nt][r] = __expf(s[r] * 0.125f);
            l_part[r] += p[nt][r];
          }
        } else {
          int k = kbs + nt * 16 + l16;
#pragma unroll
          for (int r = 0; r < 4; r++) {
            int q = q0 + w * 16 + qd * 4 + r;
            bool valid = (k < 8) || (k < LVALID && (k - q) <= WIN && (q - k) <= WIN);
            float sv = valid ? s[r] * 0.125f : -1e30f;
            p[nt][r] = __expf(sv);      // masked -> exp(-1e30) = 0 exactly
            l_part[r] += p[nt][r];
          }
        }
      }

      // P (C-layout) -> wave-private LDS -> A-layout fragments
#pragma unroll
      for (int nt = 0; nt < 4; nt++) {
        int chunk = nt * 2 + (l16 >> 3);
        int within = l16 & 7;
#pragma unroll
        for (int r = 0; r < 4; r++) {
          int qrow2 = qd * 4 + r;
          Ps[w][swz8(qrow2, chunk) * 8 + within] = f2bf(p[nt][r]);
        }
      }

      s16x8 pf0 = *(const s16x8*)(&Ps[w][0] + swz8(l16, qd) * 8);
      s16x8 pf1 = *(const s16x8*)(&Ps[w][0] + swz8(l16, 4 + qd) * 8);
#pragma unroll
      for (int nt = 0; nt < 4; nt++) {
        int vrow = nt * 16 + l16;
        s16x8 v0 = *(const s16x8*)(Vs + (vrow * 16 + ((sub * 8 + qd) ^ (vrow & 15))) * 8);
        s16x8 v1 = *(const s16x8*)(Vs + (vrow * 16 + ((sub * 8 + 4 + qd) ^ (vrow & 15))) * 8);
        aO[nt] = __builtin_amdgcn_mfma_f32_16x16x32_bf16(pf0, v0, aO[nt], 0, 0, 0);
        aO[nt] = __builtin_amdgcn_mfma_f32_16x16x32_bf16(pf1, v1, aO[nt], 0, 0, 0);
      }
    }
  }

  // one deferred row-sum reduction (16 lanes of the qd-group hold same q-row)
#pragma unroll
  for (int off = 1; off < 16; off <<= 1)
#pragma unroll
    for (int r = 0; r < 4; r++) l_part[r] += __shfl_xor(l_part[r], off);
  float inv[4];
#pragma unroll
  for (int r = 0; r < 4; r++) inv[r] = 1.0f / l_part[r];
  // rows 0..7 owned by the global path (runs first); base is 4-aligned so the
  // predicate covers all 4 r's; only (q0=0, w=0, qd<2) lanes skip.
  if ((q0 + w * 16 + qd * 4) >= 8) {
#pragma unroll
    for (int nt = 0; nt < 4; nt++)
#pragma unroll
      for (int r = 0; r < 4; r++) {
        int q = q0 + w * 16 + qd * 4 + r;
        out[(size_t)(b * LSEQ + q) * DM + h * HD + nt * 16 + l16] = aO[nt][r] * inv[r];
      }
  }
}

extern "C" void kernel_launch(void* const* d_in, const int* in_sizes, int n_in,
                              void* d_out, int out_size, void* d_ws, size_t ws_size,
                              hipStream_t stream) {
  const float* x = (const float*)d_in[0];
  float* out = (float*)d_out;
  char* ws = (char*)d_ws;

  const size_t XB_SZ = (size_t)4096 * DM * 2;
  const size_t WT_SZ = (size_t)6 * DM * DM * 2;
  const size_t MAT_SZ = (size_t)4096 * DM;
  u16* Xb = (u16*)ws;
  u16* Wt = (u16*)(ws + XB_SZ);
  u16* QKV = (u16*)(ws + XB_SZ + WT_SZ);
  u16* Vt = (u16*)(ws + XB_SZ + WT_SZ + (size_t)6 * MAT_SZ * 2);

  u16* Ql = QKV + 0 * MAT_SZ;
  u16* Kl = QKV + 1 * MAT_SZ;
  u16* Vl = QKV + 2 * MAT_SZ;
  u16* Qg = QKV + 3 * MAT_SZ;
  u16* Kg = QKV + 4 * MAT_SZ;
  u16* Vg = QKV + 5 * MAT_SZ;

  WPtrs wp;
  wp.w[0] = (const float*)d_in[1];
  wp.w[1] = (const float*)d_in[3];
  wp.w[2] = (const float*)d_in[5];
  wp.w[3] = (const float*)d_in[7];
  wp.w[4] = (const float*)d_in[9];
  wp.w[5] = (const float*)d_in[11];
  prep<<<2400, 256, 0, stream>>>(x, Xb, wp, Wt);

  GemmPtrs gp;
  const int bidx[6] = {2, 4, 6, 8, 10, 12};
  u16* outs[6] = {Ql, Kl, Vl, Qg, Kg, Vg};
  for (int i = 0; i < 6; i++) {
    gp.wt[i] = Wt + (size_t)i * DM * DM;
    gp.bias[i] = (const float*)d_in[bidx[i]];
    gp.out[i] = outs[i];
  }
  gemm6<<<252, 512, 0, stream>>>(Xb, gp);

  global_and_vt<<<240, 1024, 0, stream>>>(Qg, Kg, Vg, Vl, Vt, out);

  attn_local<<<720, 256, 0, stream>>>(Ql, Kl, Vt, out);
}